// Round 1
// baseline (635.559 us; speedup 1.0000x reference)
//
#include <hip/hip_runtime.h>
#include <cstdint>
#include <cstddef>

// ---------------------------------------------------------------------------
// SelfModifyingRecurrent: B=8192, E=1024, L=3
// Key simplifications (exact, from reference semantics):
//   * h_prev stays ZERO for all layers  -> gh = b_hh (constant), no W_hh GEMM
//   * weight modification is rank-1     -> gi += cond * 0.01*dot(cur, mean_sig)
// Compute: f16 MFMA (16x16x32) with fp32 accumulation; gate/cond in fp32.
// ---------------------------------------------------------------------------

#define BSZ 8192
#define ESZ 1024

typedef _Float16 f16x8 __attribute__((ext_vector_type(8)));
typedef float    f32x4 __attribute__((ext_vector_type(4)));
typedef unsigned short u16;
typedef u16 u16x4 __attribute__((ext_vector_type(4)));

__device__ __forceinline__ u16 f2h(float f) {
    _Float16 h = (_Float16)f;
    return __builtin_bit_cast(u16, h);
}

__device__ __forceinline__ void gload16(const void* g, void* l) {
    __builtin_amdgcn_global_load_lds((const __attribute__((address_space(1))) void*)g,
                                     (__attribute__((address_space(3))) void*)l,
                                     16, 0, 0);
}

__device__ __forceinline__ float sigmoidf_(float x) {
    return 1.f / (1.f + __expf(-x));
}
__device__ __forceinline__ float tanhf_(float x) {
    float cx = fminf(fmaxf(x, -15.f), 15.f);
    float e = __expf(2.f * cx);
    return (e - 1.f) / (e + 1.f);
}

// ---------------------------------------------------------------------------
// fp32 -> f16 conversion (vectorized), for weights and x
// ---------------------------------------------------------------------------
__global__ void cvt_f16_kernel(const float* __restrict__ in, u16* __restrict__ out, int n4) {
    int i = blockIdx.x * 256 + threadIdx.x;
    if (i >= n4) return;
    f32x4 v = ((const f32x4*)in)[i];
    u16x4 o;
    o.x = f2h(v.x); o.y = f2h(v.y); o.z = f2h(v.z); o.w = f2h(v.w);
    ((u16x4*)out)[i] = o;
}

// ---------------------------------------------------------------------------
// Gate kernel: per row r of cur (fp32):
//   gate_r = sigmoid(dot(cur_r, Wg) + bg)   -> atomic sum into gsum
//   sdot_r = dot(cur_r, colsum_sig) * (0.01/B)   (rank-1 correction, unscaled by cond)
// One wave per row, 4 rows per block.
// ---------------------------------------------------------------------------
__global__ void gate_kernel(const float* __restrict__ cur, const float* __restrict__ Wg,
                            const float* __restrict__ bg, const float* __restrict__ colsum,
                            float* __restrict__ gsum, float* __restrict__ sdot) {
    const int wid = threadIdx.x >> 6, lane = threadIdx.x & 63;
    const int row = blockIdx.x * 4 + wid;
    const float* cr = cur + (size_t)row * ESZ;
    float pg = 0.f, pm = 0.f;
#pragma unroll
    for (int c = 0; c < 4; c++) {
        int idx = c * 256 + lane * 4;
        f32x4 cv = *(const f32x4*)(cr + idx);
        f32x4 wv = *(const f32x4*)(Wg + idx);
        f32x4 mv = *(const f32x4*)(colsum + idx);
        pg += cv.x * wv.x + cv.y * wv.y + cv.z * wv.z + cv.w * wv.w;
        pm += cv.x * mv.x + cv.y * mv.y + cv.z * mv.z + cv.w * mv.w;
    }
#pragma unroll
    for (int s = 32; s >= 1; s >>= 1) {
        pg += __shfl_xor(pg, s);
        pm += __shfl_xor(pm, s);
    }
    __shared__ float gp[4];
    if (lane == 0) {
        gp[wid] = sigmoidf_(pg + bg[0]);
        sdot[row] = pm * (0.01f / 8192.f);
    }
    __syncthreads();
    if (threadIdx.x == 0) atomicAdd(gsum, gp[0] + gp[1] + gp[2] + gp[3]);
}

// ---------------------------------------------------------------------------
// Generic GEMM: C[M,N] = act(A[M,K] @ W[N,K]^T + bias)
// ACT=0: relu  -> f16 output
// ACT=1: tanh  -> f32 output + per-column sum atomics (for mean(sig, axis=0))
// 128x128 tile, BK=64, 4 waves (2x2), 16x16x32 f16 MFMA, global_load_lds staging.
// ---------------------------------------------------------------------------
template <int ACT>
__global__ void __launch_bounds__(256, 2) gemm_act_kernel(
    const u16* __restrict__ A, const u16* __restrict__ W,
    const float* __restrict__ bias, void* __restrict__ outp,
    float* __restrict__ colsum, int N, int K) {
    __shared__ u16 lA[128 * 64];
    __shared__ u16 lB[128 * 64];
    const int t = threadIdx.x;
    const int m0 = blockIdx.y * 128, n0 = blockIdx.x * 128;
    const int wid = t >> 6, lane = t & 63;
    const int waver = wid >> 1, wavec = wid & 1;
    const int lrow = lane & 15, lk = lane >> 4;

    f32x4 acc[4][4] = {};

    for (int k0 = 0; k0 < K; k0 += 64) {
        __syncthreads();
#pragma unroll
        for (int i = 0; i < 4; i++) {
            int eo = i * 2048 + t * 8;
            int r = eo >> 6, c = eo & 63;
            gload16(A + (size_t)(m0 + r) * K + k0 + c, &lA[eo]);
            gload16(W + (size_t)(n0 + r) * K + k0 + c, &lB[eo]);
        }
        __syncthreads();
#pragma unroll
        for (int kk = 0; kk < 2; kk++) {
            f16x8 af[4], bf[4];
#pragma unroll
            for (int m = 0; m < 4; m++)
                af[m] = *(const f16x8*)&lA[(waver * 64 + m * 16 + lrow) * 64 + kk * 32 + lk * 8];
#pragma unroll
            for (int n = 0; n < 4; n++)
                bf[n] = *(const f16x8*)&lB[(wavec * 64 + n * 16 + lrow) * 64 + kk * 32 + lk * 8];
#pragma unroll
            for (int m = 0; m < 4; m++)
#pragma unroll
                for (int n = 0; n < 4; n++)
                    acc[m][n] = __builtin_amdgcn_mfma_f32_16x16x32_f16(af[m], bf[n], acc[m][n], 0, 0, 0);
        }
    }

#pragma unroll
    for (int n = 0; n < 4; n++) {
        int c = n0 + wavec * 64 + n * 16 + lrow;
        float bv = bias[c];
        float cs = 0.f;
#pragma unroll
        for (int m = 0; m < 4; m++) {
            int rbase = m0 + waver * 64 + m * 16 + lk * 4;
#pragma unroll
            for (int j = 0; j < 4; j++) {
                float v = acc[m][n][j] + bv;
                if (ACT == 0) {
                    v = v > 0.f ? v : 0.f;
                    ((u16*)outp)[(size_t)(rbase + j) * N + c] = f2h(v);
                } else {
                    float tv = tanhf_(v);
                    ((float*)outp)[(size_t)(rbase + j) * N + c] = tv;
                    cs += tv;
                }
            }
        }
        if (ACT == 1) {
            cs += __shfl_xor(cs, 16);
            cs += __shfl_xor(cs, 32);
            if (lane < 16) atomicAdd(&colsum[c], cs);
        }
    }
}

// ---------------------------------------------------------------------------
// Fused GEMM3 + GRU epilogue.
// Computes gi columns {c, E+c, 2E+c} for a 128x64 output tile (3 weight-row
// groups), then applies the GRU cell with h_prev=0 and rank-1 correction:
//   i_* = gi_* + b_ih[*] + cond * sdot[row]
//   r = sig(i_r + b_hh[c]); z = sig(i_z + b_hh[E+c]); n = tanh(i_n + r*b_hh[2E+c])
//   cur_out = (1-z)*n + sig_mlp[row,c]
// Writes fp32 cur (d_out) and optionally f16 copy for next layer's GEMMs.
// ---------------------------------------------------------------------------
__global__ void __launch_bounds__(256, 2) gemm_gru_kernel(
    const u16* __restrict__ Ab, const u16* __restrict__ Wb,
    const float* __restrict__ bih, const float* __restrict__ bhh,
    const float* __restrict__ sig, const float* __restrict__ sdot,
    const float* __restrict__ gsum, float* __restrict__ curf_out,
    u16* __restrict__ curb_out) {
    __shared__ u16 lA[128 * 64];
    __shared__ u16 lB[3][64 * 64];
    const int t = threadIdx.x;
    const int m0 = blockIdx.y * 128, c0 = blockIdx.x * 64;
    const int wid = t >> 6, lane = t & 63;
    const int waver = wid >> 1, wavec = wid & 1;
    const int lrow = lane & 15, lk = lane >> 4;
    const int K = ESZ, E = ESZ;

    f32x4 acc[4][6] = {};

    for (int k0 = 0; k0 < K; k0 += 64) {
        __syncthreads();
#pragma unroll
        for (int i = 0; i < 4; i++) {
            int eo = i * 2048 + t * 8;
            int r = eo >> 6, c = eo & 63;
            gload16(Ab + (size_t)(m0 + r) * K + k0 + c, &lA[eo]);
        }
#pragma unroll
        for (int g = 0; g < 3; g++)
#pragma unroll
            for (int i = 0; i < 2; i++) {
                int eo = i * 2048 + t * 8;
                int r = eo >> 6, c = eo & 63;
                gload16(Wb + (size_t)(g * 1024 + c0 + r) * K + k0 + c, &lB[g][eo]);
            }
        __syncthreads();
#pragma unroll
        for (int kk = 0; kk < 2; kk++) {
            f16x8 af[4];
#pragma unroll
            for (int m = 0; m < 4; m++)
                af[m] = *(const f16x8*)&lA[(waver * 64 + m * 16 + lrow) * 64 + kk * 32 + lk * 8];
#pragma unroll
            for (int g = 0; g < 3; g++) {
#pragma unroll
                for (int n = 0; n < 2; n++) {
                    f16x8 bf = *(const f16x8*)&lB[g][(wavec * 32 + n * 16 + lrow) * 64 + kk * 32 + lk * 8];
#pragma unroll
                    for (int m = 0; m < 4; m++)
                        acc[m][g * 2 + n] =
                            __builtin_amdgcn_mfma_f32_16x16x32_f16(af[m], bf, acc[m][g * 2 + n], 0, 0, 0);
                }
            }
        }
    }

    const bool cond = (*gsum) > 4096.f;  // mean(gate) > 0.5
#pragma unroll
    for (int m = 0; m < 4; m++) {
        int rbase = m0 + waver * 64 + m * 16 + lk * 4;
        float corr[4];
#pragma unroll
        for (int j = 0; j < 4; j++) corr[j] = cond ? sdot[rbase + j] : 0.f;
#pragma unroll
        for (int n = 0; n < 2; n++) {
            int c = c0 + wavec * 32 + n * 16 + lrow;
            float br = bih[c], bz = bih[E + c], bn = bih[2 * E + c];
            float hr = bhh[c], hz = bhh[E + c], hn = bhh[2 * E + c];
#pragma unroll
            for (int j = 0; j < 4; j++) {
                float ir = acc[m][0 + n][j] + br + corr[j];
                float iz = acc[m][2 + n][j] + bz + corr[j];
                float inn = acc[m][4 + n][j] + bn + corr[j];
                float r = sigmoidf_(ir + hr);
                float z = sigmoidf_(iz + hz);
                float nn = tanhf_(inn + r * hn);
                float h = (1.f - z) * nn;
                float o = h + sig[(size_t)(rbase + j) * E + c];
                curf_out[(size_t)(rbase + j) * E + c] = o;
                if (curb_out) curb_out[(size_t)(rbase + j) * E + c] = f2h(o);
            }
        }
    }
}

// ---------------------------------------------------------------------------
extern "C" void kernel_launch(void* const* d_in, const int* in_sizes, int n_in,
                              void* d_out, int out_size, void* d_ws, size_t ws_size,
                              hipStream_t stream) {
    const float* x   = (const float*)d_in[0];
    const float* Wih = (const float*)d_in[1];
    // d_in[2] = W_hh : unused (h_prev == 0)
    const float* bih = (const float*)d_in[3];
    const float* bhh = (const float*)d_in[4];
    const float* W1  = (const float*)d_in[5];
    const float* b1  = (const float*)d_in[6];
    const float* W2  = (const float*)d_in[7];
    const float* b2  = (const float*)d_in[8];
    const float* Wg  = (const float*)d_in[9];
    const float* bg  = (const float*)d_in[10];
    float* out = (float*)d_out;

    char* w = (char*)d_ws;
    u16* Wihb  = (u16*)w;  w += (size_t)3 * 3072 * 1024 * 2;   // 18.9 MB
    u16* W1b   = (u16*)w;  w += (size_t)3 * 512 * 1024 * 2;    //  3.1 MB
    u16* W2b   = (u16*)w;  w += (size_t)3 * 1024 * 512 * 2;    //  3.1 MB
    u16* curbA = (u16*)w;  w += (size_t)BSZ * ESZ * 2;         // 16.8 MB
    u16* curbB = (u16*)w;  w += (size_t)BSZ * ESZ * 2;         // 16.8 MB
    u16* Amat  = (u16*)w;  w += (size_t)BSZ * 512 * 2;         //  8.4 MB
    float* sigb   = (float*)w;  w += (size_t)BSZ * ESZ * 4;    // 33.6 MB
    float* colsum = (float*)w;  w += 4096;                     // 1024 f32
    float* gsum   = (float*)w;  w += 256;                      // 1 f32 (+pad)
    float* sdot   = (float*)w;  w += (size_t)BSZ * 4;          // 32 KB

    // f16 conversions (every call — no persistent state allowed)
    {
        int n4 = 3 * 3072 * 1024 / 4;
        cvt_f16_kernel<<<dim3((n4 + 255) / 256), 256, 0, stream>>>(Wih, Wihb, n4);
        n4 = 3 * 512 * 1024 / 4;
        cvt_f16_kernel<<<dim3((n4 + 255) / 256), 256, 0, stream>>>(W1, W1b, n4);
        n4 = 3 * 1024 * 512 / 4;
        cvt_f16_kernel<<<dim3((n4 + 255) / 256), 256, 0, stream>>>(W2, W2b, n4);
        n4 = BSZ * ESZ / 4;
        cvt_f16_kernel<<<dim3((n4 + 255) / 256), 256, 0, stream>>>(x, curbA, n4);
    }

    u16* cin = curbA;
    u16* cout = curbB;
    for (int l = 0; l < 3; l++) {
        hipMemsetAsync(colsum, 0, 4096 + 4, stream);  // colsum + gsum
        // sig = tanh(relu(cur@W1^T+b1)@W2^T+b2), plus column sums
        gemm_act_kernel<0><<<dim3(512 / 128, BSZ / 128), 256, 0, stream>>>(
            cin, W1b + (size_t)l * 512 * 1024, b1 + l * 512, Amat, nullptr, 512, 1024);
        gemm_act_kernel<1><<<dim3(1024 / 128, BSZ / 128), 256, 0, stream>>>(
            Amat, W2b + (size_t)l * 1024 * 512, b2 + l * 1024, sigb, colsum, 1024, 512);
        // gate mean (-> cond) and rank-1 row dots (fp32 path)
        gate_kernel<<<dim3(BSZ / 4), 256, 0, stream>>>(
            l == 0 ? x : out, Wg + l * 1024, bg + l, colsum, gsum, sdot);
        // fused GRU: gi = cur@W_ih^T (+rank-1), elementwise cell, += sig
        gemm_gru_kernel<<<dim3(ESZ / 64, BSZ / 128), 256, 0, stream>>>(
            cin, Wihb + (size_t)l * 3072 * 1024, bih + l * 3072, bhh + l * 3072,
            sigb, sdot, gsum, out, (l < 2) ? cout : nullptr);
        u16* tmp = cin; cin = cout; cout = tmp;
    }
}

// Round 3
// 590.510 us; speedup vs baseline: 1.0763x; 1.0763x over previous
//
#include <hip/hip_runtime.h>
#include <cstdint>
#include <cstddef>

// ---------------------------------------------------------------------------
// SelfModifyingRecurrent: B=8192, E=1024, L=3
//   * h_prev stays ZERO -> gh = b_hh (const), no W_hh GEMM
//   * weight modification is rank-1 -> gi += cond * 0.01*dot(cur, mean_sig)
// f16 MFMA (16x16x32) fp32-accum. LDS XOR-swizzle (chunk ^= row&7) applied as
// pre-swizzled global source + swizzled ds_read (rule #21). sig stored f16.
// XCD-bijective block remap in gemm_gru keeps W_ih panel L2-resident.
// ---------------------------------------------------------------------------

#define BSZ 8192
#define ESZ 1024

typedef _Float16 f16x8 __attribute__((ext_vector_type(8)));
typedef float    f32x4 __attribute__((ext_vector_type(4)));
typedef unsigned short u16;
typedef u16 u16x4 __attribute__((ext_vector_type(4)));

__device__ __forceinline__ u16 f2h(float f) {
    _Float16 h = (_Float16)f;
    return __builtin_bit_cast(u16, h);
}
__device__ __forceinline__ float h2f(u16 h) {
    return (float)__builtin_bit_cast(_Float16, h);
}

__device__ __forceinline__ void gload16(const void* g, void* l) {
    __builtin_amdgcn_global_load_lds((const __attribute__((address_space(1))) void*)g,
                                     (__attribute__((address_space(3))) void*)l,
                                     16, 0, 0);
}

// swizzled LDS u16 index: row-stride 64 u16 (128B), chunk = 8-u16 (16B) slot 0..7
__device__ __forceinline__ int swzi(int row, int chunk) {
    return (row << 6) + (((chunk ^ row) & 7) << 3);
}

__device__ __forceinline__ float sigmoidf_(float x) {
    return 1.f / (1.f + __expf(-x));
}
__device__ __forceinline__ float tanhf_(float x) {
    float cx = fminf(fmaxf(x, -15.f), 15.f);
    float e = __expf(2.f * cx);
    return (e - 1.f) / (e + 1.f);
}

// ---------------------------------------------------------------------------
// fused fp32 -> f16 conversion for Wih, W1, W2, x (one launch)
// ---------------------------------------------------------------------------
#define N4_WIH (3 * 3072 * 1024 / 4)
#define N4_W1  (3 * 512 * 1024 / 4)
#define N4_W2  (3 * 1024 * 512 / 4)
#define N4_X   (BSZ * ESZ / 4)

__global__ void cvt_all_kernel(const float* __restrict__ Wih, const float* __restrict__ W1,
                               const float* __restrict__ W2, const float* __restrict__ x,
                               u16* __restrict__ oWih, u16* __restrict__ oW1,
                               u16* __restrict__ oW2, u16* __restrict__ ox) {
    int i = blockIdx.x * 256 + threadIdx.x;
    const float* in;
    u16* out;
    if (i < N4_WIH) { in = Wih; out = oWih; }
    else if (i < N4_WIH + N4_W1) { i -= N4_WIH; in = W1; out = oW1; }
    else if (i < N4_WIH + N4_W1 + N4_W2) { i -= N4_WIH + N4_W1; in = W2; out = oW2; }
    else { i -= N4_WIH + N4_W1 + N4_W2; if (i >= N4_X) return; in = x; out = ox; }
    f32x4 v = ((const f32x4*)in)[i];
    u16x4 o;
    o.x = f2h(v.x); o.y = f2h(v.y); o.z = f2h(v.z); o.w = f2h(v.w);
    ((u16x4*)out)[i] = o;
}

// ---------------------------------------------------------------------------
// Gate kernel (reads f16 cur): per row r:
//   gate_r = sigmoid(dot(cur_r, Wg) + bg)       -> atomic sum into gsum
//   sdot_r = dot(cur_r, colsum_sig)*(0.01/B)
// One wave per row, 4 rows per block; fp32 accumulate.
// ---------------------------------------------------------------------------
__global__ void gate_kernel(const u16* __restrict__ cur, const float* __restrict__ Wg,
                            const float* __restrict__ bg, const float* __restrict__ colsum,
                            float* __restrict__ gsum, float* __restrict__ sdot) {
    const int wid = threadIdx.x >> 6, lane = threadIdx.x & 63;
    const int row = blockIdx.x * 4 + wid;
    const u16* cr = cur + (size_t)row * ESZ;
    float pg = 0.f, pm = 0.f;
#pragma unroll
    for (int h = 0; h < 2; h++) {
        int base = lane * 16 + h * 8;
        f16x8 cv = *(const f16x8*)(cr + base);
#pragma unroll
        for (int q = 0; q < 2; q++) {
            f32x4 wv = *(const f32x4*)(Wg + base + q * 4);
            f32x4 mv = *(const f32x4*)(colsum + base + q * 4);
#pragma unroll
            for (int e = 0; e < 4; e++) {
                float c = (float)cv[q * 4 + e];
                pg += c * wv[e];
                pm += c * mv[e];
            }
        }
    }
#pragma unroll
    for (int s = 32; s >= 1; s >>= 1) {
        pg += __shfl_xor(pg, s);
        pm += __shfl_xor(pm, s);
    }
    __shared__ float gp[4];
    if (lane == 0) {
        gp[wid] = sigmoidf_(pg + bg[0]);
        sdot[row] = pm * (0.01f / 8192.f);
    }
    __syncthreads();
    if (threadIdx.x == 0) atomicAdd(gsum, gp[0] + gp[1] + gp[2] + gp[3]);
}

// ---------------------------------------------------------------------------
// Generic GEMM: C[M,N] = act(A[M,K] @ W[N,K]^T + bias)
// ACT=0: relu -> f16 out.  ACT=1: tanh -> f16 out + fp32 column-sum atomics.
// 128x128 tile, BK=64, 4 waves (2x2), 16x16x32 f16 MFMA, swizzled staging.
// ---------------------------------------------------------------------------
template <int ACT>
__global__ void __launch_bounds__(256, 2) gemm_act_kernel(
    const u16* __restrict__ A, const u16* __restrict__ W,
    const float* __restrict__ bias, u16* __restrict__ outp,
    float* __restrict__ colsum, int N, int K) {
    __shared__ u16 lA[128 * 64];
    __shared__ u16 lB[128 * 64];
    const int t = threadIdx.x;
    const int m0 = blockIdx.y * 128, n0 = blockIdx.x * 128;
    const int wid = t >> 6, lane = t & 63;
    const int waver = wid >> 1, wavec = wid & 1;
    const int lrow = lane & 15, lk = lane >> 4;

    f32x4 acc[4][4] = {};

    for (int k0 = 0; k0 < K; k0 += 64) {
        __syncthreads();
#pragma unroll
        for (int i = 0; i < 4; i++) {
            int eo = i * 2048 + t * 8;
            int r = eo >> 6;
            int gc = (((eo >> 3) ^ r) & 7) << 3;  // inverse(=same) swizzle on source
            gload16(A + (size_t)(m0 + r) * K + k0 + gc, &lA[eo]);
            gload16(W + (size_t)(n0 + r) * K + k0 + gc, &lB[eo]);
        }
        __syncthreads();
#pragma unroll
        for (int kk = 0; kk < 2; kk++) {
            f16x8 af[4], bf[4];
#pragma unroll
            for (int m = 0; m < 4; m++)
                af[m] = *(const f16x8*)&lA[swzi(waver * 64 + m * 16 + lrow, kk * 4 + lk)];
#pragma unroll
            for (int n = 0; n < 4; n++)
                bf[n] = *(const f16x8*)&lB[swzi(wavec * 64 + n * 16 + lrow, kk * 4 + lk)];
#pragma unroll
            for (int m = 0; m < 4; m++)
#pragma unroll
                for (int n = 0; n < 4; n++)
                    acc[m][n] = __builtin_amdgcn_mfma_f32_16x16x32_f16(af[m], bf[n], acc[m][n], 0, 0, 0);
        }
    }

#pragma unroll
    for (int n = 0; n < 4; n++) {
        int c = n0 + wavec * 64 + n * 16 + lrow;
        float bv = bias[c];
        float cs = 0.f;
#pragma unroll
        for (int m = 0; m < 4; m++) {
            int rbase = m0 + waver * 64 + m * 16 + lk * 4;
#pragma unroll
            for (int j = 0; j < 4; j++) {
                float v = acc[m][n][j] + bv;
                if (ACT == 0) {
                    v = v > 0.f ? v : 0.f;
                    outp[(size_t)(rbase + j) * N + c] = f2h(v);
                } else {
                    float tv = tanhf_(v);
                    outp[(size_t)(rbase + j) * N + c] = f2h(tv);
                    cs += tv;
                }
            }
        }
        if (ACT == 1) {
            cs += __shfl_xor(cs, 16);
            cs += __shfl_xor(cs, 32);
            if (lane < 16) atomicAdd(&colsum[c], cs);
        }
    }
}

// ---------------------------------------------------------------------------
// Fused GEMM3 + GRU epilogue. 128 rows x 64 sig-cols x 3 gate groups per block.
//   i_* = gi_* + b_ih[*] + cond*sdot[row]
//   r = sig(i_r + b_hh_r); z = sig(i_z + b_hh_z); n = tanh(i_n + r*b_hh_n)
//   cur_out = (1-z)*n + sig_mlp[row,c]
// Writes f16 cur (layers 0,1) or f32 cur==d_out (layer 2).
// ---------------------------------------------------------------------------
__global__ void __launch_bounds__(256, 2) gemm_gru_kernel(
    const u16* __restrict__ Ab, const u16* __restrict__ Wb,
    const float* __restrict__ bih, const float* __restrict__ bhh,
    const u16* __restrict__ sig, const float* __restrict__ sdot,
    const float* __restrict__ gsum, float* __restrict__ curf_out,
    u16* __restrict__ curb_out) {
    __shared__ u16 lA[128 * 64];
    __shared__ u16 lB[3][64 * 64];
    const int t = threadIdx.x;
    // XCD-bijective remap: each XCD owns 2 col-blocks x all 64 row-panels so
    // its W_ih working set (2*64 rows x3 groups x K = 786 KB) stays L2-resident.
    const int hw = blockIdx.y * 16 + blockIdx.x;
    const int xcd = hw & 7, idx = hw >> 3;
    const int m0 = (idx >> 1) * 128, c0 = ((xcd << 1) | (idx & 1)) * 64;
    const int wid = t >> 6, lane = t & 63;
    const int waver = wid >> 1, wavec = wid & 1;
    const int lrow = lane & 15, lk = lane >> 4;
    const int K = ESZ, E = ESZ;

    f32x4 acc[4][6] = {};

    for (int k0 = 0; k0 < K; k0 += 64) {
        __syncthreads();
#pragma unroll
        for (int i = 0; i < 4; i++) {
            int eo = i * 2048 + t * 8;
            int r = eo >> 6;
            int gc = (((eo >> 3) ^ r) & 7) << 3;
            gload16(Ab + (size_t)(m0 + r) * K + k0 + gc, &lA[eo]);
        }
#pragma unroll
        for (int g = 0; g < 3; g++)
#pragma unroll
            for (int i = 0; i < 2; i++) {
                int eo = i * 2048 + t * 8;
                int r = eo >> 6;
                int gc = (((eo >> 3) ^ r) & 7) << 3;
                gload16(Wb + (size_t)(g * 1024 + c0 + r) * K + k0 + gc, &lB[g][eo]);
            }
        __syncthreads();
#pragma unroll
        for (int kk = 0; kk < 2; kk++) {
            f16x8 af[4];
#pragma unroll
            for (int m = 0; m < 4; m++)
                af[m] = *(const f16x8*)&lA[swzi(waver * 64 + m * 16 + lrow, kk * 4 + lk)];
#pragma unroll
            for (int g = 0; g < 3; g++) {
#pragma unroll
                for (int n = 0; n < 2; n++) {
                    f16x8 bf = *(const f16x8*)&lB[g][swzi(wavec * 32 + n * 16 + lrow, kk * 4 + lk)];
#pragma unroll
                    for (int m = 0; m < 4; m++)
                        acc[m][g * 2 + n] =
                            __builtin_amdgcn_mfma_f32_16x16x32_f16(af[m], bf, acc[m][g * 2 + n], 0, 0, 0);
                }
            }
        }
    }

    const bool cond = (*gsum) > 4096.f;  // mean(gate) > 0.5
#pragma unroll
    for (int m = 0; m < 4; m++) {
        int rbase = m0 + waver * 64 + m * 16 + lk * 4;
        float corr[4];
#pragma unroll
        for (int j = 0; j < 4; j++) corr[j] = cond ? sdot[rbase + j] : 0.f;
#pragma unroll
        for (int n = 0; n < 2; n++) {
            int c = c0 + wavec * 32 + n * 16 + lrow;
            float br = bih[c], bz = bih[E + c], bn = bih[2 * E + c];
            float hr = bhh[c], hz = bhh[E + c], hn = bhh[2 * E + c];
#pragma unroll
            for (int j = 0; j < 4; j++) {
                float ir = acc[m][0 + n][j] + br + corr[j];
                float iz = acc[m][2 + n][j] + bz + corr[j];
                float inn = acc[m][4 + n][j] + bn + corr[j];
                float r = sigmoidf_(ir + hr);
                float z = sigmoidf_(iz + hz);
                float nn = tanhf_(inn + r * hn);
                float h = (1.f - z) * nn;
                float o = h + h2f(sig[(size_t)(rbase + j) * E + c]);
                if (curf_out) curf_out[(size_t)(rbase + j) * E + c] = o;
                if (curb_out) curb_out[(size_t)(rbase + j) * E + c] = f2h(o);
            }
        }
    }
}

// ---------------------------------------------------------------------------
extern "C" void kernel_launch(void* const* d_in, const int* in_sizes, int n_in,
                              void* d_out, int out_size, void* d_ws, size_t ws_size,
                              hipStream_t stream) {
    const float* x   = (const float*)d_in[0];
    const float* Wih = (const float*)d_in[1];
    // d_in[2] = W_hh : unused (h_prev == 0)
    const float* bih = (const float*)d_in[3];
    const float* bhh = (const float*)d_in[4];
    const float* W1  = (const float*)d_in[5];
    const float* b1  = (const float*)d_in[6];
    const float* W2  = (const float*)d_in[7];
    const float* b2  = (const float*)d_in[8];
    const float* Wg  = (const float*)d_in[9];
    const float* bg  = (const float*)d_in[10];
    float* out = (float*)d_out;

    char* w = (char*)d_ws;
    u16* Wihb  = (u16*)w;  w += (size_t)3 * 3072 * 1024 * 2;   // 18.9 MB
    u16* W1b   = (u16*)w;  w += (size_t)3 * 512 * 1024 * 2;    //  3.1 MB
    u16* W2b   = (u16*)w;  w += (size_t)3 * 1024 * 512 * 2;    //  3.1 MB
    u16* curbA = (u16*)w;  w += (size_t)BSZ * ESZ * 2;         // 16.8 MB
    u16* curbB = (u16*)w;  w += (size_t)BSZ * ESZ * 2;         // 16.8 MB
    u16* Amat  = (u16*)w;  w += (size_t)BSZ * 512 * 2;         //  8.4 MB
    u16* sigb  = (u16*)w;  w += (size_t)BSZ * ESZ * 2;         // 16.8 MB
    float* colsum = (float*)w;  w += 4096;                     // 1024 f32
    float* gsum   = (float*)w;  w += 256;                      // 1 f32 (+pad)
    float* sdot   = (float*)w;  w += (size_t)BSZ * 4;          // 32 KB

    // f16 conversions (every call — no persistent state allowed)
    {
        int n4 = N4_WIH + N4_W1 + N4_W2 + N4_X;
        cvt_all_kernel<<<dim3((n4 + 255) / 256), 256, 0, stream>>>(
            Wih, W1, W2, x, Wihb, W1b, W2b, curbA);
    }

    u16* cin = curbA;
    u16* cout = curbB;
    for (int l = 0; l < 3; l++) {
        hipMemsetAsync(colsum, 0, 4096 + 4, stream);  // colsum + gsum
        // sig = tanh(relu(cur@W1^T+b1)@W2^T+b2) (f16), plus fp32 column sums
        gemm_act_kernel<0><<<dim3(512 / 128, BSZ / 128), 256, 0, stream>>>(
            cin, W1b + (size_t)l * 512 * 1024, b1 + l * 512, Amat, nullptr, 512, 1024);
        gemm_act_kernel<1><<<dim3(1024 / 128, BSZ / 128), 256, 0, stream>>>(
            Amat, W2b + (size_t)l * 1024 * 512, b2 + l * 1024, sigb, colsum, 1024, 512);
        // gate mean (-> cond) and rank-1 row dots (fp32 accumulate, f16 cur)
        gate_kernel<<<dim3(BSZ / 4), 256, 0, stream>>>(
            cin, Wg + l * 1024, bg + l, colsum, gsum, sdot);
        // fused GRU: gi = cur@W_ih^T (+rank-1), elementwise cell, += sig
        gemm_gru_kernel<<<dim3(16, BSZ / 128), 256, 0, stream>>>(
            cin, Wihb + (size_t)l * 3072 * 1024, bih + l * 3072, bhh + l * 3072,
            sigb, sdot, gsum, (l == 2) ? out : nullptr, (l < 2) ? cout : nullptr);
        u16* tmp = cin; cin = cout; cout = tmp;
    }
}